// Round 1
// baseline (234.664 us; speedup 1.0000x reference)
//
#include <hip/hip_runtime.h>

#define LN_EPS 1e-5f

__device__ __forceinline__ float fast_rcp(float x) {
    return __builtin_amdgcn_rcpf(x);
}

__device__ __forceinline__ float silu_f(float x) {
    // x * sigmoid(x) = x / (1 + exp(-x)); exp overflow -> inf -> rcp -> 0 (correct limit)
    return x * fast_rcp(1.0f + __expf(-x));
}

__device__ __forceinline__ float tanh_f(float x) {
    float ax = fabsf(x);
    float t = __expf(-2.0f * ax);              // (0, 1]
    float r = (1.0f - t) * fast_rcp(1.0f + t);
    return copysignf(r, x);
}

__device__ __forceinline__ float softplus_f(float x) {
    // max(x,0) + log1p(exp(-|x|)); arg of log in [1,2] so logf is accurate
    float e = __expf(-fabsf(x));
    return fmaxf(x, 0.0f) + __logf(1.0f + e);
}

// One expert: h = silu(LN(x@w1 + b1) * g + bn); out = silu(h@w2 + b2)
// w1: (16,24) row-major, w2: (24,16) row-major
__device__ __forceinline__ void expert_f(const float* __restrict__ xv,
                                         const float* __restrict__ w1,
                                         const float* __restrict__ b1,
                                         const float* __restrict__ g,
                                         const float* __restrict__ bn,
                                         const float* __restrict__ w2,
                                         const float* __restrict__ b2,
                                         float* __restrict__ outv) {
    float hh[24];
    float s = 0.0f;
#pragma unroll
    for (int j = 0; j < 24; ++j) {
        float a = b1[j];
#pragma unroll
        for (int k = 0; k < 16; ++k) a = fmaf(xv[k], w1[k * 24 + j], a);
        hh[j] = a;
        s += a;
    }
    float mu = s * (1.0f / 24.0f);
    float v = 0.0f;
#pragma unroll
    for (int j = 0; j < 24; ++j) {
        float d = hh[j] - mu;
        v = fmaf(d, d, v);
    }
    float rstd = rsqrtf(fmaf(v, 1.0f / 24.0f, LN_EPS));
#pragma unroll
    for (int j = 0; j < 24; ++j) {
        float n = fmaf((hh[j] - mu) * rstd, g[j], bn[j]);
        hh[j] = silu_f(n);
    }
#pragma unroll
    for (int j = 0; j < 16; ++j) {
        float a = b2[j];
#pragma unroll
        for (int k = 0; k < 24; ++k) a = fmaf(hh[k], w2[k * 16 + j], a);
        outv[j] = silu_f(a);
    }
}

__global__ __launch_bounds__(256) void moe_fused_kernel(
    const float* __restrict__ x,
    const float* __restrict__ gw1, const float* __restrict__ gb1,
    const float* __restrict__ gw2, const float* __restrict__ gb2,
    const float* __restrict__ e1w1, const float* __restrict__ e1b1,
    const float* __restrict__ e1g, const float* __restrict__ e1bn,
    const float* __restrict__ e1w2, const float* __restrict__ e1b2,
    const float* __restrict__ e2w1, const float* __restrict__ e2b1,
    const float* __restrict__ e2g, const float* __restrict__ e2bn,
    const float* __restrict__ e2w2, const float* __restrict__ e2b2,
    const float* __restrict__ tw, const float* __restrict__ tb,
    const float* __restrict__ sw, const float* __restrict__ sb,
    const float* __restrict__ hw, const float* __restrict__ hb,
    float* __restrict__ out, int nrows) {
    int row = blockIdx.x * blockDim.x + threadIdx.x;
    if (row >= nrows) return;

    // ---- load x row (16 floats, 4x float4) ----
    float xv[16];
    const float4* xr = reinterpret_cast<const float4*>(x + (size_t)row * 16);
#pragma unroll
    for (int i = 0; i < 4; ++i) {
        float4 v = xr[i];
        xv[4 * i + 0] = v.x;
        xv[4 * i + 1] = v.y;
        xv[4 * i + 2] = v.z;
        xv[4 * i + 3] = v.w;
    }

    // ---- gate: softmax(tanh(x@gw1+gb1)@gw2+gb2) ----
    float gh[8];
#pragma unroll
    for (int j = 0; j < 8; ++j) {
        float a = gb1[j];
#pragma unroll
        for (int k = 0; k < 16; ++k) a = fmaf(xv[k], gw1[k * 8 + j], a);
        gh[j] = tanh_f(a);
    }
    float gl0 = gb2[0], gl1 = gb2[1];
#pragma unroll
    for (int k = 0; k < 8; ++k) {
        gl0 = fmaf(gh[k], gw2[k * 2 + 0], gl0);
        gl1 = fmaf(gh[k], gw2[k * 2 + 1], gl1);
    }
    float m = fmaxf(gl0, gl1);
    float e0 = __expf(gl0 - m), e1 = __expf(gl1 - m);
    float inv = fast_rcp(e0 + e1);
    float w0 = e0 * inv, w1v = e1 * inv;

    // ---- experts ----
    float h1[16], h2[16];
    expert_f(xv, e1w1, e1b1, e1g, e1bn, e1w2, e1b2, h1);
    expert_f(xv, e2w1, e2b1, e2g, e2bn, e2w2, e2b2, h2);

    float h[16];
#pragma unroll
    for (int j = 0; j < 16; ++j) h[j] = fmaf(w0, h1[j], w1v * h2[j]);

    // ---- trunk: silu(h@tw+tb) ----
    float t[16];
#pragma unroll
    for (int j = 0; j < 16; ++j) {
        float a = tb[j];
#pragma unroll
        for (int k = 0; k < 16; ++k) a = fmaf(h[k], tw[k * 16 + j], a);
        t[j] = silu_f(a);
    }

    // ---- heads ----
    float strain = sb[0];
#pragma unroll
    for (int k = 0; k < 16; ++k) strain = fmaf(t[k], sw[k], strain);
    float hs0 = hb[0], hs1 = hb[1];
#pragma unroll
    for (int k = 0; k < 16; ++k) {
        hs0 = fmaf(t[k], hw[k * 2 + 0], hs0);
        hs1 = fmaf(t[k], hw[k * 2 + 1], hs1);
    }
    float gap = softplus_f(hs1);

    size_t o = (size_t)row * 3;
    out[o + 0] = strain;
    out[o + 1] = hs0;        // tensile_raw
    out[o + 2] = hs0 - gap;  // yield_strength
}

extern "C" void kernel_launch(void* const* d_in, const int* in_sizes, int n_in,
                              void* d_out, int out_size, void* d_ws, size_t ws_size,
                              hipStream_t stream) {
    const float* x    = (const float*)d_in[0];
    const float* gw1  = (const float*)d_in[1];
    const float* gb1  = (const float*)d_in[2];
    const float* gw2  = (const float*)d_in[3];
    const float* gb2  = (const float*)d_in[4];
    const float* e1w1 = (const float*)d_in[5];
    const float* e1b1 = (const float*)d_in[6];
    const float* e1g  = (const float*)d_in[7];
    const float* e1bn = (const float*)d_in[8];
    const float* e1w2 = (const float*)d_in[9];
    const float* e1b2 = (const float*)d_in[10];
    const float* e2w1 = (const float*)d_in[11];
    const float* e2b1 = (const float*)d_in[12];
    const float* e2g  = (const float*)d_in[13];
    const float* e2bn = (const float*)d_in[14];
    const float* e2w2 = (const float*)d_in[15];
    const float* e2b2 = (const float*)d_in[16];
    const float* tw   = (const float*)d_in[17];
    const float* tb   = (const float*)d_in[18];
    const float* sw   = (const float*)d_in[19];
    const float* sb   = (const float*)d_in[20];
    const float* hw   = (const float*)d_in[21];
    const float* hb   = (const float*)d_in[22];
    float* out = (float*)d_out;

    int nrows = in_sizes[0] / 16;
    int block = 256;
    int grid = (nrows + block - 1) / block;
    moe_fused_kernel<<<grid, block, 0, stream>>>(
        x, gw1, gb1, gw2, gb2,
        e1w1, e1b1, e1g, e1bn, e1w2, e1b2,
        e2w1, e2b1, e2g, e2bn, e2w2, e2b2,
        tw, tb, sw, sb, hw, hb, out, nrows);
}

// Round 2
// 130.772 us; speedup vs baseline: 1.7945x; 1.7945x over previous
//
#include <hip/hip_runtime.h>

#define LN_EPS 1e-5f

typedef float v2f __attribute__((ext_vector_type(2)));

__device__ __forceinline__ float fast_rcp(float x) {
    return __builtin_amdgcn_rcpf(x);
}

__device__ __forceinline__ v2f ld2(const float* p) {
    return *reinterpret_cast<const v2f*>(p);
}

__device__ __forceinline__ v2f pk_fma(v2f a, v2f b, v2f c) {
    return __builtin_elementwise_fma(a, b, c);
}

__device__ __forceinline__ float silu_f(float x) {
    // x * sigmoid(x) = x / (1 + exp(-x)); exp overflow -> inf -> rcp -> 0 (correct limit)
    return x * fast_rcp(1.0f + __expf(-x));
}

__device__ __forceinline__ v2f silu2(v2f a) {
    v2f r;
    r.x = silu_f(a.x);
    r.y = silu_f(a.y);
    return r;
}

__device__ __forceinline__ float tanh_f(float x) {
    float ax = fabsf(x);
    float t = __expf(-2.0f * ax);              // (0, 1]
    float r = (1.0f - t) * fast_rcp(1.0f + t);
    return copysignf(r, x);
}

__device__ __forceinline__ float softplus_f(float x) {
    // max(x,0) + log1p(exp(-|x|)); arg of log in [1,2] so logf is accurate
    float e = __expf(-fabsf(x));
    return fmaxf(x, 0.0f) + __logf(1.0f + e);
}

// One expert, packed over output-neuron pairs.
// w1: (16,24) row-major, w2: (24,16) row-major. outv: 8 v2f = 16 outputs.
__device__ __forceinline__ void expert_pk(const float* __restrict__ xv,
                                          const float* __restrict__ w1,
                                          const float* __restrict__ b1,
                                          const float* __restrict__ g,
                                          const float* __restrict__ bn,
                                          const float* __restrict__ w2,
                                          const float* __restrict__ b2,
                                          v2f* __restrict__ outv) {
    v2f hh[12];
#pragma unroll
    for (int j = 0; j < 12; ++j) hh[j] = ld2(b1 + 2 * j);
#pragma unroll
    for (int k = 0; k < 16; ++k) {
        v2f xs = {xv[k], xv[k]};
#pragma unroll
        for (int j = 0; j < 12; ++j) hh[j] = pk_fma(xs, ld2(w1 + k * 24 + 2 * j), hh[j]);
    }
    v2f sv = hh[0];
#pragma unroll
    for (int j = 1; j < 12; ++j) sv = sv + hh[j];
    float mu = (sv.x + sv.y) * (1.0f / 24.0f);
    v2f muv = {mu, mu};
    v2f vv = {0.0f, 0.0f};
#pragma unroll
    for (int j = 0; j < 12; ++j) {
        v2f d = hh[j] - muv;
        vv = pk_fma(d, d, vv);
    }
    float rstd = rsqrtf(fmaf(vv.x + vv.y, 1.0f / 24.0f, LN_EPS));
    v2f rs = {rstd, rstd};
#pragma unroll
    for (int j = 0; j < 12; ++j) {
        v2f n = pk_fma((hh[j] - muv) * rs, ld2(g + 2 * j), ld2(bn + 2 * j));
        hh[j] = silu2(n);
    }
#pragma unroll
    for (int j = 0; j < 8; ++j) outv[j] = ld2(b2 + 2 * j);
#pragma unroll
    for (int k = 0; k < 24; ++k) {
        float hk = (k & 1) ? hh[k >> 1].y : hh[k >> 1].x;
        v2f hs = {hk, hk};
#pragma unroll
        for (int j = 0; j < 8; ++j) outv[j] = pk_fma(hs, ld2(w2 + k * 16 + 2 * j), outv[j]);
    }
#pragma unroll
    for (int j = 0; j < 8; ++j) outv[j] = silu2(outv[j]);
}

__global__ __launch_bounds__(256) void moe_fused_kernel(
    const float* __restrict__ x,
    const float* __restrict__ gw1, const float* __restrict__ gb1,
    const float* __restrict__ gw2, const float* __restrict__ gb2,
    const float* __restrict__ e1w1, const float* __restrict__ e1b1,
    const float* __restrict__ e1g, const float* __restrict__ e1bn,
    const float* __restrict__ e1w2, const float* __restrict__ e1b2,
    const float* __restrict__ e2w1, const float* __restrict__ e2b1,
    const float* __restrict__ e2g, const float* __restrict__ e2bn,
    const float* __restrict__ e2w2, const float* __restrict__ e2b2,
    const float* __restrict__ tw, const float* __restrict__ tb,
    const float* __restrict__ sw, const float* __restrict__ sb,
    const float* __restrict__ hw, const float* __restrict__ hb,
    float* __restrict__ out, int nrows) {
    int row = blockIdx.x * blockDim.x + threadIdx.x;
    if (row >= nrows) return;

    // ---- load x row (16 floats, 4x float4) ----
    float xv[16];
    const float4* xr = reinterpret_cast<const float4*>(x + (size_t)row * 16);
#pragma unroll
    for (int i = 0; i < 4; ++i) {
        float4 v = xr[i];
        xv[4 * i + 0] = v.x;
        xv[4 * i + 1] = v.y;
        xv[4 * i + 2] = v.z;
        xv[4 * i + 3] = v.w;
    }

    // ---- gate: softmax(tanh(x@gw1+gb1)@gw2+gb2) ----
    // gw1 (16,8): 4 output pairs
    v2f ga[4];
#pragma unroll
    for (int j = 0; j < 4; ++j) ga[j] = ld2(gb1 + 2 * j);
#pragma unroll
    for (int k = 0; k < 16; ++k) {
        v2f xs = {xv[k], xv[k]};
#pragma unroll
        for (int j = 0; j < 4; ++j) ga[j] = pk_fma(xs, ld2(gw1 + k * 8 + 2 * j), ga[j]);
    }
    float gh[8];
#pragma unroll
    for (int j = 0; j < 4; ++j) {
        gh[2 * j + 0] = tanh_f(ga[j].x);
        gh[2 * j + 1] = tanh_f(ga[j].y);
    }
    // gw2 (8,2): logits pair
    v2f gl = ld2(gb2);
#pragma unroll
    for (int k = 0; k < 8; ++k) {
        v2f hs = {gh[k], gh[k]};
        gl = pk_fma(hs, ld2(gw2 + 2 * k), gl);
    }
    float m = fmaxf(gl.x, gl.y);
    float e0 = __expf(gl.x - m), e1 = __expf(gl.y - m);
    float inv = fast_rcp(e0 + e1);
    float w0 = e0 * inv, w1v = e1 * inv;

    // ---- experts ----
    v2f h1[8], h2[8];
    expert_pk(xv, e1w1, e1b1, e1g, e1bn, e1w2, e1b2, h1);
    expert_pk(xv, e2w1, e2b1, e2g, e2bn, e2w2, e2b2, h2);

    v2f w0v = {w0, w0}, w1vv = {w1v, w1v};
    v2f h[8];
#pragma unroll
    for (int j = 0; j < 8; ++j) h[j] = pk_fma(w0v, h1[j], w1vv * h2[j]);

    // ---- trunk: silu(h@tw+tb), tw (16,16): 8 output pairs ----
    v2f tt[8];
#pragma unroll
    for (int j = 0; j < 8; ++j) tt[j] = ld2(tb + 2 * j);
#pragma unroll
    for (int k = 0; k < 16; ++k) {
        float hk = (k & 1) ? h[k >> 1].y : h[k >> 1].x;
        v2f hs = {hk, hk};
#pragma unroll
        for (int j = 0; j < 8; ++j) tt[j] = pk_fma(hs, ld2(tw + k * 16 + 2 * j), tt[j]);
    }
#pragma unroll
    for (int j = 0; j < 8; ++j) tt[j] = silu2(tt[j]);

    // ---- heads ----
    float strain = sb[0];
#pragma unroll
    for (int k = 0; k < 16; ++k) {
        float tk = (k & 1) ? tt[k >> 1].y : tt[k >> 1].x;
        strain = fmaf(tk, sw[k], strain);
    }
    v2f hsv = ld2(hb);
#pragma unroll
    for (int k = 0; k < 16; ++k) {
        float tk = (k & 1) ? tt[k >> 1].y : tt[k >> 1].x;
        v2f ts = {tk, tk};
        hsv = pk_fma(ts, ld2(hw + 2 * k), hsv);
    }
    float gap = softplus_f(hsv.y);

    size_t o = (size_t)row * 3;
    out[o + 0] = strain;
    out[o + 1] = hsv.x;           // tensile_raw
    out[o + 2] = hsv.x - gap;     // yield_strength
}

extern "C" void kernel_launch(void* const* d_in, const int* in_sizes, int n_in,
                              void* d_out, int out_size, void* d_ws, size_t ws_size,
                              hipStream_t stream) {
    const float* x    = (const float*)d_in[0];
    const float* gw1  = (const float*)d_in[1];
    const float* gb1  = (const float*)d_in[2];
    const float* gw2  = (const float*)d_in[3];
    const float* gb2  = (const float*)d_in[4];
    const float* e1w1 = (const float*)d_in[5];
    const float* e1b1 = (const float*)d_in[6];
    const float* e1g  = (const float*)d_in[7];
    const float* e1bn = (const float*)d_in[8];
    const float* e1w2 = (const float*)d_in[9];
    const float* e1b2 = (const float*)d_in[10];
    const float* e2w1 = (const float*)d_in[11];
    const float* e2b1 = (const float*)d_in[12];
    const float* e2g  = (const float*)d_in[13];
    const float* e2bn = (const float*)d_in[14];
    const float* e2w2 = (const float*)d_in[15];
    const float* e2b2 = (const float*)d_in[16];
    const float* tw   = (const float*)d_in[17];
    const float* tb   = (const float*)d_in[18];
    const float* sw   = (const float*)d_in[19];
    const float* sb   = (const float*)d_in[20];
    const float* hw   = (const float*)d_in[21];
    const float* hb   = (const float*)d_in[22];
    float* out = (float*)d_out;

    int nrows = in_sizes[0] / 16;
    int block = 256;
    int grid = (nrows + block - 1) / block;
    moe_fused_kernel<<<grid, block, 0, stream>>>(
        x, gw1, gb1, gw2, gb2,
        e1w1, e1b1, e1g, e1bn, e1w2, e1b2,
        e2w1, e2b1, e2g, e2bn, e2w2, e2b2,
        tw, tb, sw, sb, hw, hb, out, nrows);
}